// Round 1
// 10824.104 us; speedup vs baseline: 1.0293x; 1.0293x over previous
//
#include <hip/hip_runtime.h>
#include <math.h>

// LSTM_360 R5: dispatch-per-step, 512-thread blocks, intra-block K-split.
// Theory: stage A was 1 wave/SIMD -> memory-latency-bound. Now 8 waves/block:
//   waves (wm, wn, kh): 2x2 output tiling x 2-way K-split (K=1280 -> 640 each).
//   Each K-half accumulates into its own LDS gate buffer gs[kh]; the cell
//   update sums both. 2 waves/SIMD + half-length dependency chains.
// Per step, ONE 160-block dispatch:
//  blocks   0..127: Stage A — gates GEMM (M=128,N=4096,K=1280), block tile 64x64,
//                   wave tile 32x32 (4 acc) x 2 K-halves, + fused cell update
//  blocks 128..143: Stage B — logits_{t-1} = h_{t-1} @ Wout^T + bout (8 waves/blk)
//  blocks 144..159: Stage C — log_softmax(logits_{t-2}) -> out (8 rows/blk)
// Weight layout Wc[n][k], n = j*4+gate, so a block's 64-col slice = 16 hidden units.

#define TT  512
#define BB  128
#define NIN 256
#define NH  1024
#define G4  4096
#define KK  1280

typedef __bf16 bf16_t;
typedef bf16_t bf16x8 __attribute__((ext_vector_type(8)));
typedef float  f32x4  __attribute__((ext_vector_type(4)));

#define MFMA(a, b, c) __builtin_amdgcn_mfma_f32_16x16x32_bf16((a), (b), (c), 0, 0, 0)

// ---------------- prep kernels ----------------

__global__ void conv_w_kernel(const float* __restrict__ Wxh,
                              const float* __restrict__ Whh,
                              bf16_t* __restrict__ Wc) {
  const int n = blockIdx.y;
  const int k = blockIdx.x * 256 + threadIdx.x;
  const int g = n & 3, j = n >> 2;
  float v = (k < NIN) ? Wxh[(size_t)(g * NH + j) * NIN + k]
                      : Whh[(size_t)(g * NH + j) * NH + (k - NIN)];
  Wc[(size_t)n * KK + k] = (bf16_t)v;
}

__global__ void conv_f2b_kernel(const float* __restrict__ src,
                                bf16_t* __restrict__ dst, int n4) {
  int i = blockIdx.x * 256 + threadIdx.x;
  if (i < n4) {
    float4 v = ((const float4*)src)[i];
    dst[i * 4 + 0] = (bf16_t)v.x;
    dst[i * 4 + 1] = (bf16_t)v.y;
    dst[i * 4 + 2] = (bf16_t)v.z;
    dst[i * 4 + 3] = (bf16_t)v.w;
  }
}

__global__ void prep_bias_kernel(const float* __restrict__ bxh,
                                 const float* __restrict__ bhh,
                                 float* __restrict__ bsum4) {
  int n = blockIdx.x * 256 + threadIdx.x;  // 0..4095
  int g = n & 3, j = n >> 2;
  bsum4[n] = bxh[g * NH + j] + bhh[g * NH + j];
}

// ---------------- fused per-step kernel ----------------

__global__ __launch_bounds__(512) void fused_step(
    int t,
    const bf16_t* __restrict__ x_bf,    // [TT][BB][NIN]
    const bf16_t* __restrict__ Wc,      // [G4][KK] gate-interleaved rows
    const float*  __restrict__ bsum4,   // [G4] gate-interleaved
    const bf16_t* __restrict__ h_cur,   // [BB][NH] = h_{t-1}
    bf16_t*       __restrict__ h_next,  // [BB][NH] = h_t
    float*        __restrict__ c,       // [BB][NH]
    const bf16_t* __restrict__ WoutB,   // [NIN][NH]
    const float*  __restrict__ bout,    // [NIN]
    float*        __restrict__ logits_w,// [BB][NIN] write (step t-1)
    const float*  __restrict__ logits_r,// [BB][NIN] read  (step t-2)
    float*        __restrict__ out)     // [TT][BB][NIN]
{
  const int blk  = blockIdx.x;
  const int tid  = threadIdx.x;
  const int lane = tid & 63;
  const int wv   = tid >> 6;           // 0..7
  const int l16  = lane & 15;
  const int lq   = lane >> 4;

  if (blk < 128) {
    // ---- Stage A ----
    if (t >= TT) return;
    __shared__ float gs[2][64 * 68];   // [K-half][row=batch][col=gate], pad 68

    const int mb    = (blk & 1) * 64;
    const int ns    = blk >> 1;        // 0..63 -> 16 hidden units each
    const int nbase = ns * 64;
    const int wm = wv & 1, wn = (wv >> 1) & 1, kh = wv >> 2;
    const int m0 = mb + wm * 32;
    const int n0 = nbase + wn * 32;

    const bf16_t* ax  = x_bf + (size_t)t * BB * NIN + (size_t)(m0 + l16) * NIN + lq * 8;
    const bf16_t* ah  = h_cur + (size_t)(m0 + l16) * NH + lq * 8;
    const bf16_t* b0p = Wc + (size_t)(n0 + l16) * KK + lq * 8;
    const bf16_t* b1p = Wc + (size_t)(n0 + 16 + l16) * KK + lq * 8;

    f32x4 a00 = {0,0,0,0}, a01 = {0,0,0,0}, a10 = {0,0,0,0}, a11 = {0,0,0,0};

    if (kh == 0) {
      // x part: K chunks 0..7 (K = 256)
#pragma unroll
      for (int kk = 0; kk < 8; ++kk) {
        bf16x8 r0 = *(const bf16x8*)(ax + kk * 32);
        bf16x8 r1 = *(const bf16x8*)(ax + 16 * NIN + kk * 32);
        bf16x8 b0 = *(const bf16x8*)(b0p + kk * 32);
        bf16x8 b1 = *(const bf16x8*)(b1p + kk * 32);
        a00 = MFMA(r0, b0, a00); a01 = MFMA(r0, b1, a01);
        a10 = MFMA(r1, b0, a10); a11 = MFMA(r1, b1, a11);
      }
      // h part: chunks 0..11 (k = 0..383 of NH)
#pragma unroll 6
      for (int kk = 0; kk < 12; ++kk) {
        bf16x8 r0 = *(const bf16x8*)(ah + kk * 32);
        bf16x8 r1 = *(const bf16x8*)(ah + 16 * NH + kk * 32);
        bf16x8 b0 = *(const bf16x8*)(b0p + NIN + kk * 32);
        bf16x8 b1 = *(const bf16x8*)(b1p + NIN + kk * 32);
        a00 = MFMA(r0, b0, a00); a01 = MFMA(r0, b1, a01);
        a10 = MFMA(r1, b0, a10); a11 = MFMA(r1, b1, a11);
      }
    } else {
      // h part: chunks 12..31 (k = 384..1023 of NH)
#pragma unroll 5
      for (int kk = 12; kk < 32; ++kk) {
        bf16x8 r0 = *(const bf16x8*)(ah + kk * 32);
        bf16x8 r1 = *(const bf16x8*)(ah + 16 * NH + kk * 32);
        bf16x8 b0 = *(const bf16x8*)(b0p + NIN + kk * 32);
        bf16x8 b1 = *(const bf16x8*)(b1p + NIN + kk * 32);
        a00 = MFMA(r0, b0, a00); a01 = MFMA(r0, b1, a01);
        a10 = MFMA(r1, b0, a10); a11 = MFMA(r1, b1, a11);
      }
    }

    // D layout: col = lane&15, row = lq*4 + r
    float* g = gs[kh];
#pragma unroll
    for (int r = 0; r < 4; ++r) {
      const int rr0 = wm * 32 + lq * 4 + r;
      g[rr0 * 68 + wn * 32 + l16]             = a00[r];
      g[rr0 * 68 + wn * 32 + 16 + l16]        = a01[r];
      g[(rr0 + 16) * 68 + wn * 32 + l16]      = a10[r];
      g[(rr0 + 16) * 68 + wn * 32 + 16 + l16] = a11[r];
    }
    __syncthreads();

    // cell update: thread -> batch row b_l = tid>>3, 2 hidden units each
    const int b_l = tid >> 3;
#pragma unroll
    for (int p = 0; p < 2; ++p) {
      const int jl = (tid & 7) + p * 8;         // 0..15
      const int j  = ns * 16 + jl;              // global hidden idx
      float4 g0 = *(const float4*)&gs[0][b_l * 68 + jl * 4];
      float4 g1 = *(const float4*)&gs[1][b_l * 68 + jl * 4];
      float4 bs = ((const float4*)bsum4)[j];
      const float gi = g0.x + g1.x + bs.x;
      const float gf = g0.y + g1.y + bs.y;
      const float gg = g0.z + g1.z + bs.z;
      const float go = g0.w + g1.w + bs.w;
      const float si = 1.f / (1.f + __expf(-gi));
      const float sf = 1.f / (1.f + __expf(-gf));
      const float so = 1.f / (1.f + __expf(-go));
      const size_t idx = (size_t)(mb + b_l) * NH + j;
      const float cn = sf * c[idx] + si * tanhf(gg);
      c[idx] = cn;
      h_next[idx] = (bf16_t)(so * tanhf(cn));
    }
  } else if (blk < 144) {
    // ---- Stage B: logits for step t-1 (16 blocks x 8 waves = 128 tiles) ----
    if (t < 1 || t > TT) return;
    const int gw  = (blk - 128) * 8 + wv;       // 0..127
    const int bm0 = (gw >> 4) * 16;
    const int bn0 = (gw & 15) * 16;

    const bf16_t* ap = h_cur + (size_t)(bm0 + l16) * NH + lq * 8;
    const bf16_t* bp = WoutB + (size_t)(bn0 + l16) * NH + lq * 8;
    f32x4 acc = {0,0,0,0};
#pragma unroll 8
    for (int kk = 0; kk < 32; ++kk) {
      bf16x8 a = *(const bf16x8*)(ap + kk * 32);
      bf16x8 b = *(const bf16x8*)(bp + kk * 32);
      acc = MFMA(a, b, acc);
    }
    const float bo = bout[bn0 + l16];
#pragma unroll
    for (int r = 0; r < 4; ++r)
      logits_w[(size_t)(bm0 + lq * 4 + r) * NIN + bn0 + l16] = acc[r] + bo;
  } else {
    // ---- Stage C: log_softmax of logits_{t-2} (16 blocks x 8 rows) ----
    if (t < 2) return;
    __shared__ float red[2][2][4][4];           // [buf][sub][wave][r]
    const int sub  = tid >> 8;                  // 0/1: which 4-row group
    const int stid = tid & 255;                 // class index 0..255
    const int swv  = (tid >> 6) & 3;            // wave within sub
    const int b0 = (blk - 144) * 8 + sub * 4;
    float v[4], mx[4], sm[4];
#pragma unroll
    for (int r = 0; r < 4; ++r) v[r] = logits_r[(size_t)(b0 + r) * NIN + stid];
#pragma unroll
    for (int r = 0; r < 4; ++r) mx[r] = v[r];
#pragma unroll
    for (int off = 32; off > 0; off >>= 1)
#pragma unroll
      for (int r = 0; r < 4; ++r) mx[r] = fmaxf(mx[r], __shfl_xor(mx[r], off));
    if (lane == 0)
#pragma unroll
      for (int r = 0; r < 4; ++r) red[0][sub][swv][r] = mx[r];
    __syncthreads();
#pragma unroll
    for (int r = 0; r < 4; ++r)
      mx[r] = fmaxf(fmaxf(red[0][sub][0][r], red[0][sub][1][r]),
                    fmaxf(red[0][sub][2][r], red[0][sub][3][r]));
#pragma unroll
    for (int r = 0; r < 4; ++r) sm[r] = __expf(v[r] - mx[r]);
#pragma unroll
    for (int off = 32; off > 0; off >>= 1)
#pragma unroll
      for (int r = 0; r < 4; ++r) sm[r] += __shfl_xor(sm[r], off);
    if (lane == 0)
#pragma unroll
      for (int r = 0; r < 4; ++r) red[1][sub][swv][r] = sm[r];
    __syncthreads();
    float* ot = out + (size_t)(t - 2) * BB * NIN + (size_t)b0 * NIN;
#pragma unroll
    for (int r = 0; r < 4; ++r) {
      float S = red[1][sub][0][r] + red[1][sub][1][r] +
                red[1][sub][2][r] + red[1][sub][3][r];
      ot[(size_t)r * NIN + stid] = v[r] - mx[r] - logf(S);
    }
  }
}

// ---------------- launcher ----------------

extern "C" void kernel_launch(void* const* d_in, const int* in_sizes, int n_in,
                              void* d_out, int out_size, void* d_ws, size_t ws_size,
                              hipStream_t stream) {
  const float* inp  = (const float*)d_in[0];
  const float* Wxh  = (const float*)d_in[1];
  const float* bxh  = (const float*)d_in[2];
  const float* Whh  = (const float*)d_in[3];
  const float* bhh  = (const float*)d_in[4];
  const float* Wout = (const float*)d_in[5];
  const float* bout = (const float*)d_in[6];
  float* out = (float*)d_out;

  // workspace carve (~46 MB)
  char* p = (char*)d_ws;
  bf16_t* Wc    = (bf16_t*)p; p += (size_t)G4 * KK * 2;        // 10.49 MB
  bf16_t* x_bf  = (bf16_t*)p; p += (size_t)TT * BB * NIN * 2;  // 33.55 MB
  bf16_t* WoutB = (bf16_t*)p; p += (size_t)NIN * NH * 2;       // 0.52 MB
  bf16_t* h0    = (bf16_t*)p; p += (size_t)BB * NH * 2;
  bf16_t* h1    = (bf16_t*)p; p += (size_t)BB * NH * 2;
  float*  cbuf  = (float*)p;  p += (size_t)BB * NH * 4;
  float*  bsum4 = (float*)p;  p += (size_t)G4 * 4;
  float*  lg0   = (float*)p;  p += (size_t)BB * NIN * 4;
  float*  lg1   = (float*)p;  p += (size_t)BB * NIN * 4;

  conv_w_kernel<<<dim3(KK / 256, G4), 256, 0, stream>>>(Wxh, Whh, Wc);
  conv_f2b_kernel<<<(TT * BB * NIN / 4 + 255) / 256, 256, 0, stream>>>(
      inp, x_bf, TT * BB * NIN / 4);
  conv_f2b_kernel<<<(NIN * NH / 4 + 255) / 256, 256, 0, stream>>>(
      Wout, WoutB, NIN * NH / 4);
  prep_bias_kernel<<<G4 / 256, 256, 0, stream>>>(bxh, bhh, bsum4);
  hipMemsetAsync(h0, 0, (size_t)BB * NH * 2, stream);
  hipMemsetAsync(cbuf, 0, (size_t)BB * NH * 4, stream);

  bf16_t* hb[2] = {h0, h1};
  float*  lg[2] = {lg0, lg1};
  for (int t = 0; t < TT + 2; ++t) {
    fused_step<<<160, 512, 0, stream>>>(
        t, x_bf, Wc, bsum4,
        hb[t & 1], hb[(t + 1) & 1], cbuf,
        WoutB, bout,
        lg[t & 1],        // write: logits for step t-1
        lg[(t + 1) & 1],  // read:  logits for step t-2
        out);
  }
}